// Round 8
// baseline (1002.577 us; speedup 1.0000x reference)
//
#include <hip/hip_runtime.h>
#include <hip/hip_bf16.h>

#define N_NODES 50000
#define N_EDGES 1000000
#define NCLS 27   // C+1

typedef short s8v __attribute__((ext_vector_type(8)));   // 8 x bf16 bits (4 VGPR)
typedef float f4v __attribute__((ext_vector_type(4)));   // MFMA acc

__device__ __forceinline__ ushort f2bf(float f) {
    __hip_bfloat16 h = __float2bfloat16(f);
    return *reinterpret_cast<ushort*>(&h);
}

// ---------------------------------------------------------------------------
// Fused prologue (one launch, all parts concurrent):
//  blocks [0,3125)    : cat table  [N][64] bf16 (16 nodes/block)
//  blocks [3125,3253) : SW = subj_W@W1a, OW = obj_W@W1c -> B-frag layout
//  block  3253        : TW1 = trans_W@W1b (fp32), b1p = folded biases
//  blocks [3254,3398) : pack W2, W3(pad 32) -> B-frag layout
// B-frag packed idx: ((ks*NT+nt)*64 + hi*16+lo)*8 + j == B[k=ks*32+hi*8+j][nt*16+lo]
// ---------------------------------------------------------------------------
__global__ __launch_bounds__(256) void k_prep(
    const int* __restrict__ ori, const float* __restrict__ dim,
    const float* __restrict__ otab, const float* __restrict__ sW,
    const float* __restrict__ sb,
    const float* __restrict__ subj_W, const float* __restrict__ subj_b,
    const float* __restrict__ obj_W,  const float* __restrict__ obj_b,
    const float* __restrict__ trans_W, const float* __restrict__ trans_b,
    const float* __restrict__ W1, const float* __restrict__ b1,
    const float* __restrict__ W2, const float* __restrict__ W3,
    ushort* __restrict__ cat, ushort* __restrict__ SWp, ushort* __restrict__ OWp,
    float* __restrict__ TW1, float* __restrict__ b1p,
    ushort* __restrict__ W2p, ushort* __restrict__ W3p)
{
    const int b = blockIdx.x, t = threadIdx.x;
    if (b < 3125) {                         // ---- cat ----
#pragma unroll
        for (int it = 0; it < 4; ++it) {
            const int n = b * 16 + it * 4 + (t >> 6);
            const int c = t & 63;
            float v;
            if (c < 32)
                v = sb[c] + dim[n*3]*sW[c] + dim[n*3+1]*sW[32+c] + dim[n*3+2]*sW[64+c];
            else
                v = otab[ori[n]*32 + (c - 32)];
            cat[n*64 + c] = f2bf(v);
        }
    } else if (b < 3253) {                  // ---- fold SW/OW ----
        const int idx = (b - 3125) * 256 + t;      // 0..32767
        const int which = idx >> 14;
        const int e = idx & 16383;
        const int k = e >> 8;                      // 0..63
        const int n = e & 255;                     // 0..255
        const float* A = which ? obj_W : subj_W;
        const float* B = which ? (W1 + 256*256) : W1;
        float s = 0.f;
        for (int q = 0; q < 128; ++q) s += A[k*128 + q] * B[q*256 + n];
        const int ks = k >> 5, j = k & 7, hi = (k >> 3) & 3, nt = n >> 4, lo = n & 15;
        ushort* P = which ? OWp : SWp;
        P[((ks*16 + nt)*64 + hi*16 + lo)*8 + j] = f2bf(s);
    } else if (b == 3253) {                 // ---- TW1 / b1p ----
        const int n = t;
        float t0 = 0, t1 = 0, t2 = 0, bb = b1[n];
        for (int q = 0; q < 128; ++q) {
            const float wb = W1[(128 + q)*256 + n];
            t0 += trans_W[q]       * wb;
            t1 += trans_W[128 + q] * wb;
            t2 += trans_W[256 + q] * wb;
            bb += trans_b[q] * wb;
            bb += subj_b[q] * W1[q*256 + n];
            bb += obj_b[q]  * W1[(256 + q)*256 + n];
        }
        TW1[n] = t0; TW1[256 + n] = t1; TW1[512 + n] = t2; b1p[n] = bb;
    } else {                                // ---- pack W2/W3 ----
        const int idx = (b - 3254) * 256 + t;      // 0..36863
        if (idx < 32768) {
            const int g = idx >> 9, k = g >> 3, nt = g & 7;
            const int lane = (idx >> 3) & 63, j = idx & 7;
            W2p[idx] = f2bf(W2[(k*32 + (lane >> 4)*8 + j)*128 + nt*16 + (lane & 15)]);
        } else {
            const int e = idx - 32768;
            const int g = e >> 9, k = g >> 1, nt = g & 1;
            const int lane = (e >> 3) & 63, j = e & 7;
            const int col = nt*16 + (lane & 15);
            const int r = k*32 + (lane >> 4)*8 + j;
            W3p[e] = f2bf((col < NCLS) ? W3[r*NCLS + col] : 0.f);
        }
    }
}

// ---------------------------------------------------------------------------
// Main: fused edge MLP, MFMA. 64 edges/block, 256 thr (4 waves).
// Wave w: GEMM1 cols [w*64,+64), GEMM2 cols [w*32,+32), GEMM3 m-tile w.
// All weight fragments + A gathers preloaded at block start (LDS-bound
// occupancy: 4 blocks/CU regardless of VGPR; spend registers freely).
// GEMM1 K = 64(subj)+64(obj)+32(extra: [d0,d1,d2,1] x [TW1;b1p] fold).
// LDS h: h1 bf16[64][256] swizzled (byte ^= (row&7)<<4); h2 [64][128] aliases.
// ---------------------------------------------------------------------------
__global__ __launch_bounds__(256, 4) void edge_mfma(
    const float* __restrict__ loc, const int* __restrict__ src, const int* __restrict__ dst,
    const ushort* __restrict__ cat, const ushort* __restrict__ SWp, const ushort* __restrict__ OWp,
    const ushort* __restrict__ W2p, const ushort* __restrict__ W3p,
    const float* __restrict__ TW1, const float* __restrict__ b1p,
    const float* __restrict__ b2, const float* __restrict__ b3,
    float* __restrict__ out)
{
    __shared__ ushort h[16384];     // 32 KB
    __shared__ float diffs[64][4];  // 1 KB

    const int t = threadIdx.x, lane = t & 63, w = t >> 6;
    const int lo = lane & 15, hi = lane >> 4;
    const int eb = blockIdx.x * 64;

    // (1) diffs staging (needed only at the extra-K MFMA, after barrier 1)
    if (t < 64) {
        const int s = src[eb + t], d = dst[eb + t];
        diffs[t][0] = loc[s*3]     - loc[d*3];
        diffs[t][1] = loc[s*3 + 1] - loc[d*3 + 1];
        diffs[t][2] = loc[s*3 + 2] - loc[d*3 + 2];
    }
    // (2) gather indices
    int sidx[4], didx[4];
#pragma unroll
    for (int m = 0; m < 4; ++m) {
        sidx[m] = src[eb + m*16 + lo];
        didx[m] = dst[eb + m*16 + lo];
    }

    const s8v* catv = (const s8v*)cat;
    const s8v* swv  = (const s8v*)SWp;
    const s8v* owv  = (const s8v*)OWp;
    const s8v* w2v  = (const s8v*)W2p;
    const s8v* w3v  = (const s8v*)W3p;

    // (3) all weight-fragment loads issued up front (L2-hot, fill gather gap)
    s8v Bs[2][4], Bo[2][4];
#pragma unroll
    for (int ks = 0; ks < 2; ++ks)
#pragma unroll
        for (int nt = 0; nt < 4; ++nt) {
            Bs[ks][nt] = swv[(ks*16 + w*4 + nt)*64 + lane];
            Bo[ks][nt] = owv[(ks*16 + w*4 + nt)*64 + lane];
        }
    s8v w2f[8][2];
#pragma unroll
    for (int k = 0; k < 8; ++k)
#pragma unroll
        for (int nt = 0; nt < 2; ++nt)
            w2f[k][nt] = w2v[(k*8 + w*2 + nt)*64 + lane];
    s8v w3f[4][2];
#pragma unroll
    for (int k = 0; k < 4; ++k)
#pragma unroll
        for (int nt = 0; nt < 2; ++nt)
            w3f[k][nt] = w3v[(k*2 + nt)*64 + lane];

    // (4) extra-K B fragment: rows 0-2 = TW1, row 3 = b1p (hi==0 lanes only)
    s8v Bx[4];
#pragma unroll
    for (int nt = 0; nt < 4; ++nt) {
        s8v bx = (s8v){0,0,0,0,0,0,0,0};
        if (hi == 0) {
            const int col = w*64 + nt*16 + lo;
            bx[0] = (short)f2bf(TW1[col]);
            bx[1] = (short)f2bf(TW1[256 + col]);
            bx[2] = (short)f2bf(TW1[512 + col]);
            bx[3] = (short)f2bf(b1p[col]);
        }
        Bx[nt] = bx;
    }

    // (5) A-fragment gathers (sidx has returned by now)
    s8v As[4][2], Ao[4][2];
#pragma unroll
    for (int m = 0; m < 4; ++m) {
        As[m][0] = catv[(size_t)sidx[m]*8 + hi];
        As[m][1] = catv[(size_t)sidx[m]*8 + 4 + hi];
        Ao[m][0] = catv[(size_t)didx[m]*8 + hi];
        Ao[m][1] = catv[(size_t)didx[m]*8 + 4 + hi];
    }

    // (6) GEMM1: k-outer order -> 16 independent MFMAs per group
    f4v acc1[4][4];
#pragma unroll
    for (int m = 0; m < 4; ++m)
#pragma unroll
        for (int nt = 0; nt < 4; ++nt) acc1[m][nt] = (f4v){0.f, 0.f, 0.f, 0.f};

#pragma unroll
    for (int ks = 0; ks < 2; ++ks)
#pragma unroll
        for (int m = 0; m < 4; ++m)
#pragma unroll
            for (int nt = 0; nt < 4; ++nt)
                acc1[m][nt] = __builtin_amdgcn_mfma_f32_16x16x32_bf16(As[m][ks], Bs[ks][nt], acc1[m][nt], 0, 0, 0);
#pragma unroll
    for (int ks = 0; ks < 2; ++ks)
#pragma unroll
        for (int m = 0; m < 4; ++m)
#pragma unroll
            for (int nt = 0; nt < 4; ++nt)
                acc1[m][nt] = __builtin_amdgcn_mfma_f32_16x16x32_bf16(Ao[m][ks], Bo[ks][nt], acc1[m][nt], 0, 0, 0);

    __syncthreads();   // diffs visible

    // (7) extra-K: A_x = [d0,d1,d2,1], folds diff@TW1 + b1p
    s8v Ax[4];
#pragma unroll
    for (int m = 0; m < 4; ++m) {
        s8v ax = (s8v){0,0,0,0,0,0,0,0};
        if (hi == 0) {
            const int row = m*16 + lo;
            ax[0] = (short)f2bf(diffs[row][0]);
            ax[1] = (short)f2bf(diffs[row][1]);
            ax[2] = (short)f2bf(diffs[row][2]);
            ax[3] = (short)0x3F80;   // 1.0 bf16
        }
        Ax[m] = ax;
    }
#pragma unroll
    for (int m = 0; m < 4; ++m)
#pragma unroll
        for (int nt = 0; nt < 4; ++nt)
            acc1[m][nt] = __builtin_amdgcn_mfma_f32_16x16x32_bf16(Ax[m], Bx[nt], acc1[m][nt], 0, 0, 0);

    // (8) epilogue 1: relu + cvt + swizzled LDS write (bias already folded)
#pragma unroll
    for (int m = 0; m < 4; ++m)
#pragma unroll
        for (int r = 0; r < 4; ++r) {
            const int row = m*16 + hi*4 + r;
#pragma unroll
            for (int nt = 0; nt < 4; ++nt) {
                const float v = fmaxf(acc1[m][nt][r], 0.f);
                const int col = w*64 + nt*16 + lo;
                const int addr = (row*512 + col*2) ^ ((row & 7) << 4);
                *(ushort*)((char*)h + addr) = f2bf(v);
            }
        }
    __syncthreads();

    // (9) GEMM2: h2 = relu(h1 @ W2 + b2)
    f4v acc2[4][2];
#pragma unroll
    for (int m = 0; m < 4; ++m)
#pragma unroll
        for (int nt = 0; nt < 2; ++nt) acc2[m][nt] = (f4v){0.f, 0.f, 0.f, 0.f};
#pragma unroll
    for (int k = 0; k < 8; ++k) {
        s8v a[4];
#pragma unroll
        for (int m = 0; m < 4; ++m) {
            const int row = m*16 + lo;
            const int addr = (row*512 + k*64 + hi*16) ^ ((row & 7) << 4);
            a[m] = *(const s8v*)((char*)h + addr);
        }
#pragma unroll
        for (int m = 0; m < 4; ++m)
#pragma unroll
            for (int nt = 0; nt < 2; ++nt)
                acc2[m][nt] = __builtin_amdgcn_mfma_f32_16x16x32_bf16(a[m], w2f[k][nt], acc2[m][nt], 0, 0, 0);
    }
    __syncthreads();   // all h1 reads done before h2 overwrites

    {
        float b2v[2];
#pragma unroll
        for (int nt = 0; nt < 2; ++nt) b2v[nt] = b2[w*32 + nt*16 + lo];
#pragma unroll
        for (int m = 0; m < 4; ++m)
#pragma unroll
            for (int nt = 0; nt < 2; ++nt)
#pragma unroll
                for (int r = 0; r < 4; ++r) {
                    const int row = m*16 + hi*4 + r;
                    const int col = w*32 + nt*16 + lo;
                    const float v = fmaxf(acc2[m][nt][r] + b2v[nt], 0.f);
                    const int addr = (row*256 + col*2) ^ ((row & 7) << 4);
                    *(ushort*)((char*)h + addr) = f2bf(v);
                }
    }
    __syncthreads();

    // (10) GEMM3: scores = h2 @ W3(pad32) + b3; wave w owns m-tile w
    f4v acc3[2];
#pragma unroll
    for (int nt = 0; nt < 2; ++nt) acc3[nt] = (f4v){0.f, 0.f, 0.f, 0.f};
#pragma unroll
    for (int k = 0; k < 4; ++k) {
        const int row = w*16 + lo;
        const int addr = (row*256 + k*64 + hi*16) ^ ((row & 7) << 4);
        const s8v a = *(const s8v*)((char*)h + addr);
#pragma unroll
        for (int nt = 0; nt < 2; ++nt)
            acc3[nt] = __builtin_amdgcn_mfma_f32_16x16x32_bf16(a, w3f[k][nt], acc3[nt], 0, 0, 0);
    }
#pragma unroll
    for (int nt = 0; nt < 2; ++nt) {
        const int col = nt*16 + lo;
        if (col < NCLS) {
            const float bb = b3[col];
#pragma unroll
            for (int r = 0; r < 4; ++r) {
                const int e = eb + w*16 + hi*4 + r;
                out[(size_t)e*NCLS + col] = acc3[nt][r] + bb;
            }
        }
    }
}

// ---------------------------------------------------------------------------
// targets -> float copy, vectorized (int4 -> float4)
// ---------------------------------------------------------------------------
__global__ __launch_bounds__(256) void targets_copy4(
    const int* __restrict__ targets, float* __restrict__ out_tail)
{
    const int i = blockIdx.x * blockDim.x + threadIdx.x;
    if (i < N_EDGES / 4) {
        const int4 v = ((const int4*)targets)[i];
        float4 r;
        r.x = (float)v.x; r.y = (float)v.y; r.z = (float)v.z; r.w = (float)v.w;
        ((float4*)out_tail)[i] = r;
    }
}

// ---------------------------------------------------------------------------
extern "C" void kernel_launch(void* const* d_in, const int* in_sizes, int n_in,
                              void* d_out, int out_size, void* d_ws, size_t ws_size,
                              hipStream_t stream) {
    const int*   orientation  = (const int*)  d_in[0];
    const float* dimension    = (const float*)d_in[1];
    const float* location     = (const float*)d_in[2];
    const int*   src          = (const int*)  d_in[3];
    const int*   dst          = (const int*)  d_in[4];
    const int*   targets      = (const int*)  d_in[5];
    const float* orient_table = (const float*)d_in[6];
    const float* size_W       = (const float*)d_in[7];
    const float* size_b       = (const float*)d_in[8];
    const float* subj_W       = (const float*)d_in[9];
    const float* subj_b       = (const float*)d_in[10];
    const float* obj_W        = (const float*)d_in[11];
    const float* obj_b        = (const float*)d_in[12];
    const float* trans_W      = (const float*)d_in[13];
    const float* trans_b      = (const float*)d_in[14];
    const float* W1           = (const float*)d_in[15];
    const float* b1           = (const float*)d_in[16];
    const float* W2           = (const float*)d_in[17];
    const float* b2           = (const float*)d_in[18];
    const float* W3           = (const float*)d_in[19];
    const float* b3           = (const float*)d_in[20];

    char* ws = (char*)d_ws;
    ushort* cat = (ushort*)(ws);                 // 6,400,000 B
    ushort* SWp = (ushort*)(ws + 6400000);       // 32,768 B
    ushort* OWp = (ushort*)(ws + 6432768);       // 32,768 B
    ushort* W2p = (ushort*)(ws + 6465536);       // 65,536 B
    ushort* W3p = (ushort*)(ws + 6531072);       //  8,192 B
    float*  TW1 = (float*) (ws + 6539264);       //  3,072 B
    float*  b1p = (float*) (ws + 6542336);       //  1,024 B
    float*  out = (float*)d_out;

    k_prep<<<3398, 256, 0, stream>>>(
        orientation, dimension, orient_table, size_W, size_b,
        subj_W, subj_b, obj_W, obj_b, trans_W, trans_b,
        W1, b1, W2, W3,
        cat, SWp, OWp, TW1, b1p, W2p, W3p);

    edge_mfma<<<N_EDGES / 64, 256, 0, stream>>>(
        location, src, dst, cat, SWp, OWp, W2p, W3p, TW1, b1p, b2, b3, out);

    targets_copy4<<<(N_EDGES / 4 + 255) / 256, 256, 0, stream>>>(
        targets, out + (size_t)N_EDGES * NCLS);
}

// Round 15
// 445.185 us; speedup vs baseline: 2.2520x; 2.2520x over previous
//
#include <hip/hip_runtime.h>
#include <hip/hip_bf16.h>

#define N_NODES 50000
#define N_EDGES 1000000
#define NCLS 27   // C+1

typedef short s8v __attribute__((ext_vector_type(8)));   // 8 x bf16 bits (4 VGPR)
typedef float f4v __attribute__((ext_vector_type(4)));   // MFMA acc

__device__ __forceinline__ ushort f2bf(float f) {
    __hip_bfloat16 h = __float2bfloat16(f);
    return *reinterpret_cast<ushort*>(&h);
}

// ---------------------------------------------------------------------------
// Fused prologue (one launch, all parts concurrent):
//  blocks [0,3125)    : cat table  [N][64] bf16 (16 nodes/block)
//  blocks [3125,3253) : SW = subj_W@W1a, OW = obj_W@W1c -> B-frag layout
//  block  3253        : TW1 = trans_W@W1b (fp32), b1p = folded biases
//  blocks [3254,3398) : pack W2, W3(pad 32) -> B-frag layout
// B-frag packed idx: ((ks*NT+nt)*64 + hi*16+lo)*8 + j == B[k=ks*32+hi*8+j][nt*16+lo]
// ---------------------------------------------------------------------------
__global__ __launch_bounds__(256) void k_prep(
    const int* __restrict__ ori, const float* __restrict__ dim,
    const float* __restrict__ otab, const float* __restrict__ sW,
    const float* __restrict__ sb,
    const float* __restrict__ subj_W, const float* __restrict__ subj_b,
    const float* __restrict__ obj_W,  const float* __restrict__ obj_b,
    const float* __restrict__ trans_W, const float* __restrict__ trans_b,
    const float* __restrict__ W1, const float* __restrict__ b1,
    const float* __restrict__ W2, const float* __restrict__ W3,
    ushort* __restrict__ cat, ushort* __restrict__ SWp, ushort* __restrict__ OWp,
    float* __restrict__ TW1, float* __restrict__ b1p,
    ushort* __restrict__ W2p, ushort* __restrict__ W3p)
{
    const int b = blockIdx.x, t = threadIdx.x;
    if (b < 3125) {                         // ---- cat ----
#pragma unroll
        for (int it = 0; it < 4; ++it) {
            const int n = b * 16 + it * 4 + (t >> 6);
            const int c = t & 63;
            float v;
            if (c < 32)
                v = sb[c] + dim[n*3]*sW[c] + dim[n*3+1]*sW[32+c] + dim[n*3+2]*sW[64+c];
            else
                v = otab[ori[n]*32 + (c - 32)];
            cat[n*64 + c] = f2bf(v);
        }
    } else if (b < 3253) {                  // ---- fold SW/OW ----
        const int idx = (b - 3125) * 256 + t;      // 0..32767
        const int which = idx >> 14;
        const int e = idx & 16383;
        const int k = e >> 8;                      // 0..63
        const int n = e & 255;                     // 0..255
        const float* A = which ? obj_W : subj_W;
        const float* B = which ? (W1 + 256*256) : W1;
        float s = 0.f;
        for (int q = 0; q < 128; ++q) s += A[k*128 + q] * B[q*256 + n];
        const int ks = k >> 5, j = k & 7, hi = (k >> 3) & 3, nt = n >> 4, lo = n & 15;
        ushort* P = which ? OWp : SWp;
        P[((ks*16 + nt)*64 + hi*16 + lo)*8 + j] = f2bf(s);
    } else if (b == 3253) {                 // ---- TW1 / b1p ----
        const int n = t;
        float t0 = 0, t1 = 0, t2 = 0, bb = b1[n];
        for (int q = 0; q < 128; ++q) {
            const float wb = W1[(128 + q)*256 + n];
            t0 += trans_W[q]       * wb;
            t1 += trans_W[128 + q] * wb;
            t2 += trans_W[256 + q] * wb;
            bb += trans_b[q] * wb;
            bb += subj_b[q] * W1[q*256 + n];
            bb += obj_b[q]  * W1[(256 + q)*256 + n];
        }
        TW1[n] = t0; TW1[256 + n] = t1; TW1[512 + n] = t2; b1p[n] = bb;
    } else {                                // ---- pack W2/W3 ----
        const int idx = (b - 3254) * 256 + t;      // 0..36863
        if (idx < 32768) {
            const int g = idx >> 9, k = g >> 3, nt = g & 7;
            const int lane = (idx >> 3) & 63, j = idx & 7;
            W2p[idx] = f2bf(W2[(k*32 + (lane >> 4)*8 + j)*128 + nt*16 + (lane & 15)]);
        } else {
            const int e = idx - 32768;
            const int g = e >> 9, k = g >> 1, nt = g & 1;
            const int lane = (e >> 3) & 63, j = e & 7;
            const int col = nt*16 + (lane & 15);
            const int r = k*32 + (lane >> 4)*8 + j;
            W3p[e] = f2bf((col < NCLS) ? W3[r*NCLS + col] : 0.f);
        }
    }
}

// ---------------------------------------------------------------------------
// Main: fused edge MLP, MFMA. 64 edges/block, 256 thr (4 waves).
// Wave w: GEMM1 cols [w*64,+64), GEMM2 cols [w*32,+32), GEMM3 m-tile w.
// Register discipline (round-8 lesson: NO min-waves hint — unified VGPR+AGPR
// budget made __launch_bounds__(256,4) cap regs at 128/wave and spill 3.5GB):
//   preload only GEMM1 operands (A gathers + Bs/Bo + Bx  ~= 208 live regs);
//   w2f issued after GEMM1 (hidden by extra-K+epilogue1+barrier);
//   w3f issued after GEMM2 k-loop (hidden by epilogue2+barrier).
// GEMM1 K = 64(subj)+64(obj)+32(extra: [d0,d1,d2,1] x [TW1;b1p] fold).
// LDS h: h1 bf16[64][256] swizzled (byte ^= (row&7)<<4); h2 [64][128] aliases.
// ---------------------------------------------------------------------------
__global__ __launch_bounds__(256) void edge_mfma(
    const float* __restrict__ loc, const int* __restrict__ src, const int* __restrict__ dst,
    const ushort* __restrict__ cat, const ushort* __restrict__ SWp, const ushort* __restrict__ OWp,
    const ushort* __restrict__ W2p, const ushort* __restrict__ W3p,
    const float* __restrict__ TW1, const float* __restrict__ b1p,
    const float* __restrict__ b2, const float* __restrict__ b3,
    float* __restrict__ out)
{
    __shared__ ushort h[16384];     // 32 KB
    __shared__ float diffs[64][4];  // 1 KB

    const int t = threadIdx.x, lane = t & 63, w = t >> 6;
    const int lo = lane & 15, hi = lane >> 4;
    const int eb = blockIdx.x * 64;

    // (1) diffs staging (consumed at the extra-K MFMA, after barrier 1)
    if (t < 64) {
        const int s = src[eb + t], d = dst[eb + t];
        diffs[t][0] = loc[s*3]     - loc[d*3];
        diffs[t][1] = loc[s*3 + 1] - loc[d*3 + 1];
        diffs[t][2] = loc[s*3 + 2] - loc[d*3 + 2];
    }
    // (2) gather indices
    int sidx[4], didx[4];
#pragma unroll
    for (int m = 0; m < 4; ++m) {
        sidx[m] = src[eb + m*16 + lo];
        didx[m] = dst[eb + m*16 + lo];
    }

    const s8v* catv = (const s8v*)cat;
    const s8v* swv  = (const s8v*)SWp;
    const s8v* owv  = (const s8v*)OWp;
    const s8v* w2v  = (const s8v*)W2p;
    const s8v* w3v  = (const s8v*)W3p;

    // (3) A-fragment gathers — the long-latency loads, issued first
    s8v As[4][2], Ao[4][2];
#pragma unroll
    for (int m = 0; m < 4; ++m) {
        As[m][0] = catv[(size_t)sidx[m]*8 + hi];
        As[m][1] = catv[(size_t)sidx[m]*8 + 4 + hi];
        Ao[m][0] = catv[(size_t)didx[m]*8 + hi];
        Ao[m][1] = catv[(size_t)didx[m]*8 + 4 + hi];
    }

    // (4) GEMM1 B fragments (L2-hot)
    s8v Bs[2][4], Bo[2][4];
#pragma unroll
    for (int ks = 0; ks < 2; ++ks)
#pragma unroll
        for (int nt = 0; nt < 4; ++nt) {
            Bs[ks][nt] = swv[(ks*16 + w*4 + nt)*64 + lane];
            Bo[ks][nt] = owv[(ks*16 + w*4 + nt)*64 + lane];
        }

    // (5) extra-K B fragment: rows 0-2 = TW1, row 3 = b1p (hi==0 lanes only)
    s8v Bx[4];
#pragma unroll
    for (int nt = 0; nt < 4; ++nt) {
        s8v bx = (s8v){0,0,0,0,0,0,0,0};
        if (hi == 0) {
            const int col = w*64 + nt*16 + lo;
            bx[0] = (short)f2bf(TW1[col]);
            bx[1] = (short)f2bf(TW1[256 + col]);
            bx[2] = (short)f2bf(TW1[512 + col]);
            bx[3] = (short)f2bf(b1p[col]);
        }
        Bx[nt] = bx;
    }

    // (6) GEMM1: k-outer order -> 16 independent MFMAs per k-chunk
    f4v acc1[4][4];
#pragma unroll
    for (int m = 0; m < 4; ++m)
#pragma unroll
        for (int nt = 0; nt < 4; ++nt) acc1[m][nt] = (f4v){0.f, 0.f, 0.f, 0.f};

#pragma unroll
    for (int ks = 0; ks < 2; ++ks)
#pragma unroll
        for (int m = 0; m < 4; ++m)
#pragma unroll
            for (int nt = 0; nt < 4; ++nt)
                acc1[m][nt] = __builtin_amdgcn_mfma_f32_16x16x32_bf16(As[m][ks], Bs[ks][nt], acc1[m][nt], 0, 0, 0);
#pragma unroll
    for (int ks = 0; ks < 2; ++ks)
#pragma unroll
        for (int m = 0; m < 4; ++m)
#pragma unroll
            for (int nt = 0; nt < 4; ++nt)
                acc1[m][nt] = __builtin_amdgcn_mfma_f32_16x16x32_bf16(Ao[m][ks], Bo[ks][nt], acc1[m][nt], 0, 0, 0);

    // (7) issue W2 fragments NOW — A/B regs dead, latency hidden by
    //     extra-K + epilogue-1 + barrier
    s8v w2f[8][2];
#pragma unroll
    for (int k = 0; k < 8; ++k)
#pragma unroll
        for (int nt = 0; nt < 2; ++nt)
            w2f[k][nt] = w2v[(k*8 + w*2 + nt)*64 + lane];

    __syncthreads();   // diffs visible

    // (8) extra-K: A_x = [d0,d1,d2,1], folds diff@TW1 + b1p
    s8v Ax[4];
#pragma unroll
    for (int m = 0; m < 4; ++m) {
        s8v ax = (s8v){0,0,0,0,0,0,0,0};
        if (hi == 0) {
            const int row = m*16 + lo;
            ax[0] = (short)f2bf(diffs[row][0]);
            ax[1] = (short)f2bf(diffs[row][1]);
            ax[2] = (short)f2bf(diffs[row][2]);
            ax[3] = (short)0x3F80;   // 1.0 bf16
        }
        Ax[m] = ax;
    }
#pragma unroll
    for (int m = 0; m < 4; ++m)
#pragma unroll
        for (int nt = 0; nt < 4; ++nt)
            acc1[m][nt] = __builtin_amdgcn_mfma_f32_16x16x32_bf16(Ax[m], Bx[nt], acc1[m][nt], 0, 0, 0);

    // (9) epilogue 1: relu + cvt + swizzled LDS write (bias already folded)
#pragma unroll
    for (int m = 0; m < 4; ++m)
#pragma unroll
        for (int r = 0; r < 4; ++r) {
            const int row = m*16 + hi*4 + r;
#pragma unroll
            for (int nt = 0; nt < 4; ++nt) {
                const float v = fmaxf(acc1[m][nt][r], 0.f);
                const int col = w*64 + nt*16 + lo;
                const int addr = (row*512 + col*2) ^ ((row & 7) << 4);
                *(ushort*)((char*)h + addr) = f2bf(v);
            }
        }
    __syncthreads();

    // (10) GEMM2: h2 = relu(h1 @ W2 + b2)
    f4v acc2[4][2];
#pragma unroll
    for (int m = 0; m < 4; ++m)
#pragma unroll
        for (int nt = 0; nt < 2; ++nt) acc2[m][nt] = (f4v){0.f, 0.f, 0.f, 0.f};
#pragma unroll
    for (int k = 0; k < 8; ++k) {
        s8v a[4];
#pragma unroll
        for (int m = 0; m < 4; ++m) {
            const int row = m*16 + lo;
            const int addr = (row*512 + k*64 + hi*16) ^ ((row & 7) << 4);
            a[m] = *(const s8v*)((char*)h + addr);
        }
#pragma unroll
        for (int m = 0; m < 4; ++m)
#pragma unroll
            for (int nt = 0; nt < 2; ++nt)
                acc2[m][nt] = __builtin_amdgcn_mfma_f32_16x16x32_bf16(a[m], w2f[k][nt], acc2[m][nt], 0, 0, 0);
    }

    // (11) issue W3 fragments NOW — hidden by epilogue-2 + barrier
    s8v w3f[4][2];
#pragma unroll
    for (int k = 0; k < 4; ++k)
#pragma unroll
        for (int nt = 0; nt < 2; ++nt)
            w3f[k][nt] = w3v[(k*2 + nt)*64 + lane];

    __syncthreads();   // all h1 reads done before h2 overwrites

    {
        float b2v[2];
#pragma unroll
        for (int nt = 0; nt < 2; ++nt) b2v[nt] = b2[w*32 + nt*16 + lo];
#pragma unroll
        for (int m = 0; m < 4; ++m)
#pragma unroll
            for (int nt = 0; nt < 2; ++nt)
#pragma unroll
                for (int r = 0; r < 4; ++r) {
                    const int row = m*16 + hi*4 + r;
                    const int col = w*32 + nt*16 + lo;
                    const float v = fmaxf(acc2[m][nt][r] + b2v[nt], 0.f);
                    const int addr = (row*256 + col*2) ^ ((row & 7) << 4);
                    *(ushort*)((char*)h + addr) = f2bf(v);
                }
    }
    __syncthreads();

    // (12) GEMM3: scores = h2 @ W3(pad32) + b3; wave w owns m-tile w
    f4v acc3[2];
#pragma unroll
    for (int nt = 0; nt < 2; ++nt) acc3[nt] = (f4v){0.f, 0.f, 0.f, 0.f};
#pragma unroll
    for (int k = 0; k < 4; ++k) {
        const int row = w*16 + lo;
        const int addr = (row*256 + k*64 + hi*16) ^ ((row & 7) << 4);
        const s8v a = *(const s8v*)((char*)h + addr);
#pragma unroll
        for (int nt = 0; nt < 2; ++nt)
            acc3[nt] = __builtin_amdgcn_mfma_f32_16x16x32_bf16(a, w3f[k][nt], acc3[nt], 0, 0, 0);
    }
#pragma unroll
    for (int nt = 0; nt < 2; ++nt) {
        const int col = nt*16 + lo;
        if (col < NCLS) {
            const float bb = b3[col];
#pragma unroll
            for (int r = 0; r < 4; ++r) {
                const int e = eb + w*16 + hi*4 + r;
                out[(size_t)e*NCLS + col] = acc3[nt][r] + bb;
            }
        }
    }
}

// ---------------------------------------------------------------------------
// targets -> float copy, vectorized (int4 -> float4)
// ---------------------------------------------------------------------------
__global__ __launch_bounds__(256) void targets_copy4(
    const int* __restrict__ targets, float* __restrict__ out_tail)
{
    const int i = blockIdx.x * blockDim.x + threadIdx.x;
    if (i < N_EDGES / 4) {
        const int4 v = ((const int4*)targets)[i];
        float4 r;
        r.x = (float)v.x; r.y = (float)v.y; r.z = (float)v.z; r.w = (float)v.w;
        ((float4*)out_tail)[i] = r;
    }
}

// ---------------------------------------------------------------------------
extern "C" void kernel_launch(void* const* d_in, const int* in_sizes, int n_in,
                              void* d_out, int out_size, void* d_ws, size_t ws_size,
                              hipStream_t stream) {
    const int*   orientation  = (const int*)  d_in[0];
    const float* dimension    = (const float*)d_in[1];
    const float* location     = (const float*)d_in[2];
    const int*   src          = (const int*)  d_in[3];
    const int*   dst          = (const int*)  d_in[4];
    const int*   targets      = (const int*)  d_in[5];
    const float* orient_table = (const float*)d_in[6];
    const float* size_W       = (const float*)d_in[7];
    const float* size_b       = (const float*)d_in[8];
    const float* subj_W       = (const float*)d_in[9];
    const float* subj_b       = (const float*)d_in[10];
    const float* obj_W        = (const float*)d_in[11];
    const float* obj_b        = (const float*)d_in[12];
    const float* trans_W      = (const float*)d_in[13];
    const float* trans_b      = (const float*)d_in[14];
    const float* W1           = (const float*)d_in[15];
    const float* b1           = (const float*)d_in[16];
    const float* W2           = (const float*)d_in[17];
    const float* b2           = (const float*)d_in[18];
    const float* W3           = (const float*)d_in[19];
    const float* b3           = (const float*)d_in[20];

    char* ws = (char*)d_ws;
    ushort* cat = (ushort*)(ws);                 // 6,400,000 B
    ushort* SWp = (ushort*)(ws + 6400000);       // 32,768 B
    ushort* OWp = (ushort*)(ws + 6432768);       // 32,768 B
    ushort* W2p = (ushort*)(ws + 6465536);       // 65,536 B
    ushort* W3p = (ushort*)(ws + 6531072);       //  8,192 B
    float*  TW1 = (float*) (ws + 6539264);       //  3,072 B
    float*  b1p = (float*) (ws + 6542336);       //  1,024 B
    float*  out = (float*)d_out;

    k_prep<<<3398, 256, 0, stream>>>(
        orientation, dimension, orient_table, size_W, size_b,
        subj_W, subj_b, obj_W, obj_b, trans_W, trans_b,
        W1, b1, W2, W3,
        cat, SWp, OWp, TW1, b1p, W2p, W3p);

    edge_mfma<<<N_EDGES / 64, 256, 0, stream>>>(
        location, src, dst, cat, SWp, OWp, W2p, W3p, TW1, b1p, b2, b3, out);

    targets_copy4<<<(N_EDGES / 4 + 255) / 256, 256, 0, stream>>>(
        targets, out + (size_t)N_EDGES * NCLS);
}